// Round 9
// baseline (267.009 us; speedup 1.0000x reference)
//
#include <hip/hip_runtime.h>
#include <math.h>

#define TT 4096
#define DD 1024
#define HH 768
#define NE 23
#define NG 24          // 23 experts + shared as group 23
#define BM 256
#define BN 128
#define BK 64
#define MAXT 88        // sum ceil(n_e/256) <= 71, + 16 shared tiles = 87
#define KB1 16         // DD/64
#define KB2 12         // HH/64
#define NY1 6          // HH/BN
#define NY2 8          // DD/BN
#define NWG1 (MAXT*NY1)   // 528  (div by 8)
#define NWG2 (MAXT*NY2)   // 704  (div by 8)

// ws word offsets (misc, < 512KB)
#define WS_CURS   0        // 23*16 ints (1 cache line per expert)
#define WS_COUNTS 512
#define WS_PSUM   544
#define WS_OFFS   576
#define WS_TOFFS  608
#define WS_TOTAL  640
#define WS_T2E    672      // tile -> expert/group
#define WS_T2A    832      // tile -> a0
#define WS_TOKE   1024
#define WS_TOKW   13312
#define WS_LTOK   25600
#define WS_LW     41984
#define WS_PPART  58368    // 23*1024 floats
#define WS_CPART  81920    // 23*1024 ints (ends 105472)
#define WS_SIDX   106496   // 12288 ints (ends 118784 < 131072)
// ws byte offsets (big buffers)
#define XB_OFF  ((size_t)524288)      // xb bf16: 4096*1024*2  = 8388608
#define H_OFF   ((size_t)8912896)     // H  bf16: (12288+4096+pad)*768*2
#define W1B_OFF ((size_t)34078720)    // W1 blocked bf16: 24*16*768*64*2 = 37748736
                                      //   (reused after mm1 as yslot)
#define W2B_OFF ((size_t)71827456)    // W2 blocked bf16: 24*12*1024*64*2 = 37748736

typedef short bf16x8 __attribute__((ext_vector_type(8)));
typedef float f32x4 __attribute__((ext_vector_type(4)));
typedef unsigned short u16x8 __attribute__((ext_vector_type(8)));

#define S_BARRIER() asm volatile("s_barrier" ::: "memory")
#define WAIT_VM6()  asm volatile("s_waitcnt vmcnt(6)" ::: "memory")
#define WAIT_VM0()  asm volatile("s_waitcnt vmcnt(0)" ::: "memory")

__device__ inline unsigned short bfr(float f) {   // f32 -> bf16 RNE
    unsigned u = __float_as_uint(f);
    u += 0x7fffu + ((u >> 16) & 1u);
    return (unsigned short)(u >> 16);
}
__device__ inline float b2f(unsigned short u) {
    return __uint_as_float((unsigned)u << 16);
}

__device__ __forceinline__ void gl_lds16(const void* g, void* l) {
    __builtin_amdgcn_global_load_lds(
        (const __attribute__((address_space(1))) unsigned int*)g,
        (__attribute__((address_space(3))) unsigned int*)l, 16, 0, 0);
}

// gating + x->bf16 conversion fused (x already staged in LDS)
__global__ __launch_bounds__(256) void k_gate(
    const float* __restrict__ x, const float* __restrict__ gW,
    const float* __restrict__ gb, const float* __restrict__ bias,
    int* __restrict__ tokE, float* __restrict__ tokW,
    float* __restrict__ Ppart, int* __restrict__ Cpart,
    unsigned short* __restrict__ xb)
{
    __shared__ float xs[4][DD];
    __shared__ float gv[4][NE];
    __shared__ float ginvs[4];
    __shared__ int sel[4][3];
    const int tid = threadIdx.x;
    const int t0 = blockIdx.x * 4;
    {
        const float4* src = (const float4*)(x + (size_t)t0 * DD);
        float4* dst = (float4*)&xs[0][0];
        #pragma unroll
        for (int i = 0; i < 4; i++) dst[tid + 256 * i] = src[tid + 256 * i];
    }
    __syncthreads();
    {   // write bf16 copy of the 4 staged tokens
        const float* xf = &xs[0][0];
        unsigned short* xd = xb + (size_t)t0 * DD;
        #pragma unroll
        for (int it = 0; it < 4; it++) {
            int o = it * 1024 + tid * 4;
            ushort4 u = make_ushort4(bfr(xf[o]), bfr(xf[o + 1]), bfr(xf[o + 2]), bfr(xf[o + 3]));
            *(ushort4*)(xd + o) = u;
        }
    }
    const int w = tid >> 6, l = tid & 63;
    const int t = t0 + w;
    if (l < NE) {
        float s0 = 0.f, s1 = 0.f, s2 = 0.f, s3 = 0.f;
        const float* xw = xs[w];
        for (int d = 0; d < DD; d += 4) {
            s0 = fmaf(xw[d + 0], gW[(d + 0) * NE + l], s0);
            s1 = fmaf(xw[d + 1], gW[(d + 1) * NE + l], s1);
            s2 = fmaf(xw[d + 2], gW[(d + 2) * NE + l], s2);
            s3 = fmaf(xw[d + 3], gW[(d + 3) * NE + l], s3);
        }
        float s = (s0 + s1) + (s2 + s3) + gb[l];
        gv[w][l] = 1.f / (1.f + expf(-s));
    }
    __syncthreads();
    if (l == 0) {
        unsigned chosen = 0;
        int be[3]; float bw[3];
        float gsum = 0.f;
        for (int e = 0; e < NE; e++) gsum += gv[w][e];
        #pragma unroll
        for (int k = 0; k < 3; k++) {
            float m = -1e30f; int mi = 0;
            for (int e = 0; e < NE; e++) {
                float kv = gv[w][e] + bias[e];
                if (!((chosen >> e) & 1u) && kv > m) { m = kv; mi = e; }
            }
            chosen |= 1u << mi;
            be[k] = mi; bw[k] = gv[w][mi];
        }
        float inv = 1.f / (bw[0] + bw[1] + bw[2]);
        #pragma unroll
        for (int k = 0; k < 3; k++) {
            tokE[t * 3 + k] = be[k];
            tokW[t * 3 + k] = bw[k] * inv;
            sel[w][k] = be[k];
        }
        ginvs[w] = 1.f / gsum;
    }
    __syncthreads();
    if (tid < NE) {   // per-block partials: NO global atomics
        float p = gv[0][tid] * ginvs[0] + gv[1][tid] * ginvs[1]
                + gv[2][tid] * ginvs[2] + gv[3][tid] * ginvs[3];
        Ppart[tid * 1024 + blockIdx.x] = p;
        int c = 0;
        #pragma unroll
        for (int w2 = 0; w2 < 4; w2++)
            #pragma unroll
            for (int k = 0; k < 3; k++) c += (sel[w2][k] == tid);
        Cpart[tid * 1024 + blockIdx.x] = c;
    }
}

__global__ __launch_bounds__(256) void k_reduce(
    const float* __restrict__ Ppart, const int* __restrict__ Cpart,
    int* __restrict__ counts, float* __restrict__ Psum)
{
    const int e = blockIdx.x;
    const int tid = threadIdx.x;
    float s = 0.f; int c = 0;
    for (int i = tid; i < 1024; i += 256) {
        s += Ppart[e * 1024 + i];
        c += Cpart[e * 1024 + i];
    }
    #pragma unroll
    for (int off = 32; off >= 1; off >>= 1) {
        s += __shfl_down(s, off, 64);
        c += __shfl_down(c, off, 64);
    }
    __shared__ float ss[4]; __shared__ int sc[4];
    if ((tid & 63) == 0) { ss[tid >> 6] = s; sc[tid >> 6] = c; }
    __syncthreads();
    if (tid == 0) {
        Psum[e] = ss[0] + ss[1] + ss[2] + ss[3];
        counts[e] = sc[0] + sc[1] + sc[2] + sc[3];
    }
}

__global__ void k_scan(const int* __restrict__ counts, const float* __restrict__ Psum,
                       int* __restrict__ offs, int* __restrict__ toffs,
                       int* __restrict__ total, int* __restrict__ t2e,
                       int* __restrict__ t2a, float* __restrict__ outAux)
{
    if (threadIdx.x != 0 || blockIdx.x != 0) return;
    int off = 0, toff = 0;
    for (int e = 0; e < NG; e++) {
        int c = (e < NE) ? counts[e] : TT;
        offs[e] = off; toffs[e] = toff;
        int nt = (c + BM - 1) / BM;
        for (int t = 0; t < nt; t++) {
            t2e[toff + t] = e;
            t2a[toff + t] = off + t * BM;
        }
        off += c; toff += nt;
    }
    offs[NG] = off; toffs[NG] = toff;
    *total = toff;
    float aux = 0.f;
    for (int e = 0; e < NE; e++) {
        float P = Psum[e] / (float)TT;
        float F = (float)NE * (float)counts[e] / (float)(3 * TT);
        aux += P * F;
    }
    outAux[0] = aux;
    for (int e = 0; e < NE; e++) outAux[1 + e] = (float)counts[e];
}

__global__ void k_scatter(const int* __restrict__ tokE, const float* __restrict__ tokW,
                          const int* __restrict__ offs, int* __restrict__ curs,
                          int* __restrict__ ltok, float* __restrict__ lw,
                          int* __restrict__ sidx)
{
    int t = blockIdx.x * 256 + threadIdx.x;
    if (t >= TT) return;
    #pragma unroll
    for (int k = 0; k < 3; k++) {
        int e = tokE[t * 3 + k];
        int pos = atomicAdd(&curs[e * 16], 1);
        int idx = offs[e] + pos;
        ltok[idx] = t; lw[idx] = tokW[t * 3 + k];
        sidx[t * 3 + k] = idx;
    }
    ltok[3 * TT + t] = t;
    lw[3 * TT + t] = 1.f;
}

// W [K][N] f32 -> blocked transposed bf16, 64-k blocks, XOR swizzle baked in:
// dst[((e*(K/64)+kb)*N + n)*64 + p*8 + i] = bf16(W[kb*64 + j*8 + i][n]), p = j ^ (n&7)
__global__ __launch_bounds__(256) void k_cvt_w(
    const float* __restrict__ W, const float* __restrict__ Ws,
    int K, int N, unsigned short* __restrict__ dst)
{
    const int e = blockIdx.z, kb = blockIdx.y;
    const int KBt = gridDim.y;
    const int n0 = blockIdx.x * 64;
    const float* src = (e < NE) ? (W + (size_t)e * K * N) : Ws;
    __shared__ unsigned short Ls[64][66];
    const int tid = threadIdx.x;
    const int c = (tid & 15) * 4, r0 = tid >> 4;
    #pragma unroll
    for (int pass = 0; pass < 4; pass++) {
        int row = pass * 16 + r0;
        float4 v = *(const float4*)(src + (size_t)(kb * 64 + row) * N + n0 + c);
        ushort4 u = make_ushort4(bfr(v.x), bfr(v.y), bfr(v.z), bfr(v.w));
        *(ushort4*)&Ls[row][c] = u;
    }
    __syncthreads();
    unsigned short* dbase = dst + ((size_t)(e * KBt + kb) * N + n0) * 64;
    #pragma unroll
    for (int half = 0; half < 2; half++) {
        int g = half * 256 + tid;
        int n = g >> 3, p = g & 7;
        int j = p ^ (n & 7);
        u16x8 u;
        #pragma unroll
        for (int i = 0; i < 8; i++) u[i] = Ls[j * 8 + i][n];
        *(u16x8*)(dbase + n * 64 + p * 8) = u;   // consecutive tid -> consecutive 16B
    }
}

// grouped bf16-MFMA GEMM1 + fast GeLU; 8-wave 256x128 tile, depth-2 stage-early
// pipeline (3-buffer ring, counted vmcnt(6), ONE barrier per K-step)
__global__ __launch_bounds__(512) void k_mm1(
    const unsigned short* __restrict__ xb, const unsigned short* __restrict__ W1b,
    const float* __restrict__ b1, const float* __restrict__ sb1,
    const int* __restrict__ t2e, const int* __restrict__ t2a,
    const int* __restrict__ offs, const int* __restrict__ total,
    const int* __restrict__ ltok, unsigned short* __restrict__ H)
{
    const int id = blockIdx.x;
    const int wg = (id & 7) * (NWG1 / 8) + (id >> 3);   // XCD-aware bijective swizzle
    const int ns = wg / MAXT;
    const int tb = wg % MAXT;
    if (tb >= *total) return;
    const int e = t2e[tb];
    const int a0 = t2a[tb];
    const int acount = min(offs[e + 1] - a0, BM);
    const float* bb = (e < NE) ? (b1 + e * HH) : sb1;
    const int nb = ns * BN;

    __shared__ unsigned short As[3][BM * BK];   // 3 x 32 KB
    __shared__ unsigned short Bs[3][BN * BK];   // 3 x 16 KB
    __shared__ int rows[BM];
    const int tid = threadIdx.x;
    if (tid < BM) rows[tid] = ltok[a0 + min(tid, acount - 1)];  // clamped gather
    __syncthreads();

    const int wid = tid >> 6, lane = tid & 63;
    const int wr = wid & 3, wc = wid >> 2;      // 4 row-groups x 2 col-groups of 64
    const int l15 = lane & 15, l4 = lane >> 4;

    float bv[4];
    #pragma unroll
    for (int n = 0; n < 4; n++) bv[n] = bb[nb + wc * 64 + n * 16 + l15];

    f32x4 acc[4][4];
    #pragma unroll
    for (int m = 0; m < 4; m++)
        #pragma unroll
        for (int n = 0; n < 4; n++) acc[m][n] = (f32x4){0.f, 0.f, 0.f, 0.f};

    // per-lane staging addresses: A = 4 granules, B = 2 granules per thread per tile
    const unsigned short* aSrc[4];
    int GA[4], GB[2];
    #pragma unroll
    for (int c = 0; c < 4; c++) {
        int G = c * 512 + tid;           // 0..2047
        int row = G >> 3, j = G & 7;
        aSrc[c] = xb + (size_t)rows[row] * DD + ((j ^ (row & 7)) << 3);
        GA[c] = G * 8;
    }
    #pragma unroll
    for (int c = 0; c < 2; c++) GB[c] = (c * 512 + tid) * 8;   // 0..1023 granules
    const unsigned short* wbase = W1b + ((size_t)e * KB1 * HH + nb) * 64;

    auto stage = [&](int buf, int kb) {   // 6 VMEM ops per thread
        #pragma unroll
        for (int c = 0; c < 4; c++)
            gl_lds16(aSrc[c] + kb * 64, &As[buf][GA[c]]);
        const unsigned short* wb = wbase + (size_t)kb * (HH * 64);
        #pragma unroll
        for (int c = 0; c < 2; c++)
            gl_lds16(wb + GB[c], &Bs[buf][GB[c]]);
    };
    auto compute = [&](int buf) {
        #pragma unroll
        for (int kh = 0; kh < 2; kh++) {
            bf16x8 af[4], bf[4];
            #pragma unroll
            for (int f = 0; f < 4; f++) {
                int ar = wr * 64 + f * 16 + l15;
                int br = wc * 64 + f * 16 + l15;
                int pg = (kh << 2) + l4;
                af[f] = *(const bf16x8*)&As[buf][ar * 64 + ((pg ^ (ar & 7)) << 3)];
                bf[f] = *(const bf16x8*)&Bs[buf][br * 64 + ((pg ^ (br & 7)) << 3)];
            }
            #pragma unroll
            for (int m = 0; m < 4; m++)
                #pragma unroll
                for (int n = 0; n < 4; n++)
                    acc[m][n] = __builtin_amdgcn_mfma_f32_16x16x32_bf16(af[m], bf[n], acc[m][n], 0, 0, 0);
        }
    };

    stage(0, 0);
    stage(1, 1);
    WAIT_VM6();            // outstanding 12 -> wait to 6: tile 0 landed
    S_BARRIER();
    int cur = 0;
    #pragma unroll 1
    for (int kb = 0; kb < KB1; kb++) {
        if (kb + 2 < KB1) stage((cur + 2) % 3, kb + 2);   // issue 2-ahead FIRST
        __builtin_amdgcn_sched_barrier(0);                 // pin: stage before compute
        compute(cur);
        if (kb + 1 < KB1) {
            if (kb + 2 < KB1) WAIT_VM6();   // {kb+1:6, kb+2:6} -> retire kb+1
            else              WAIT_VM0();   // only {kb+1:6} left
            S_BARRIER();
        }
        cur = (cur == 2) ? 0 : cur + 1;
    }

    #pragma unroll
    for (int m = 0; m < 4; m++) {
        int rbase = wr * 64 + m * 16 + l4 * 4;
        #pragma unroll
        for (int n = 0; n < 4; n++) {
            int col = nb + wc * 64 + n * 16 + l15;
            #pragma unroll
            for (int i = 0; i < 4; i++) {
                int r = rbase + i;
                if (r < acount) {
                    float v = acc[m][n][i] + bv[n];
                    float u = v + 0.044715f * v * v * v;
                    float g = v / (1.f + __expf(-1.5957691216f * u));  // tanh-gelu
                    H[(size_t)(a0 + r) * HH + col] = bfr(g);
                }
            }
        }
    }
}

// grouped bf16-MFMA GEMM2; 8-wave 256x128 tile, depth-2 stage-early pipeline.
// expert tiles -> weighted bf16 slot stores; shared tile -> plain f32 out stores
__global__ __launch_bounds__(512) void k_mm2(
    const unsigned short* __restrict__ H, const unsigned short* __restrict__ W2b,
    const float* __restrict__ b2, const float* __restrict__ sb2,
    const int* __restrict__ t2e, const int* __restrict__ t2a,
    const int* __restrict__ offs, const int* __restrict__ total,
    const int* __restrict__ ltok, const float* __restrict__ lw,
    unsigned short* __restrict__ yslot, float* __restrict__ out)
{
    const int id = blockIdx.x;
    const int wg = (id & 7) * (NWG2 / 8) + (id >> 3);
    const int ns = wg / MAXT;
    const int tb = wg % MAXT;
    if (tb >= *total) return;
    const int e = t2e[tb];
    const int a0 = t2a[tb];
    const int acount = min(offs[e + 1] - a0, BM);
    const float* bb = (e < NE) ? (b2 + e * DD) : sb2;
    const int nb = ns * BN;

    __shared__ unsigned short As[3][BM * BK];
    __shared__ unsigned short Bs[3][BN * BK];
    __shared__ int rows[BM];
    __shared__ float wts[BM];
    const int tid = threadIdx.x;
    if (tid < BM) {
        rows[tid] = (tid < acount) ? ltok[a0 + tid] : -1;
        wts[tid]  = (tid < acount) ? lw[a0 + tid] : 0.f;
    }
    __syncthreads();

    const int wid = tid >> 6, lane = tid & 63;
    const int wr = wid & 3, wc = wid >> 2;
    const int l15 = lane & 15, l4 = lane >> 4;

    float bv[4];
    #pragma unroll
    for (int n = 0; n < 4; n++) bv[n] = bb[nb + wc * 64 + n * 16 + l15];

    f32x4 acc[4][4];
    #pragma unroll
    for (int m = 0; m < 4; m++)
        #pragma unroll
        for (int n = 0; n < 4; n++) acc[m][n] = (f32x4){0.f, 0.f, 0.f, 0.f};

    const unsigned short* aSrc[4];
    int GA[4], GB[2];
    #pragma unroll
    for (int c = 0; c < 4; c++) {
        int G = c * 512 + tid;
        int row = G >> 3, j = G & 7;
        aSrc[c] = H + (size_t)(a0 + row) * HH + ((j ^ (row & 7)) << 3);  // contiguous rows
        GA[c] = G * 8;
    }
    #pragma unroll
    for (int c = 0; c < 2; c++) GB[c] = (c * 512 + tid) * 8;
    const unsigned short* wbase = W2b + ((size_t)e * KB2 * DD + nb) * 64;

    auto stage = [&](int buf, int kb) {
        #pragma unroll
        for (int c = 0; c < 4; c++)
            gl_lds16(aSrc[c] + kb * 64, &As[buf][GA[c]]);
        const unsigned short* wb = wbase + (size_t)kb * (DD * 64);
        #pragma unroll
        for (int c = 0; c < 2; c++)
            gl_lds16(wb + GB[c], &Bs[buf][GB[c]]);
    };
    auto compute = [&](int buf) {
        #pragma unroll
        for (int kh = 0; kh < 2; kh++) {
            bf16x8 af[4], bf[4];
            #pragma unroll
            for (int f = 0; f < 4; f++) {
                int ar = wr * 64 + f * 16 + l15;
                int br = wc * 64 + f * 16 + l15;
                int pg = (kh << 2) + l4;
                af[f] = *(const bf16x8*)&As[buf][ar * 64 + ((pg ^ (ar & 7)) << 3)];
                bf[f] = *(const bf16x8*)&Bs[buf][br * 64 + ((pg ^ (br & 7)) << 3)];
            }
            #pragma unroll
            for (int m = 0; m < 4; m++)
                #pragma unroll
                for (int n = 0; n < 4; n++)
                    acc[m][n] = __builtin_amdgcn_mfma_f32_16x16x32_bf16(af[m], bf[n], acc[m][n], 0, 0, 0);
        }
    };

    stage(0, 0);
    stage(1, 1);
    WAIT_VM6();
    S_BARRIER();
    int cur = 0;
    #pragma unroll 1
    for (int kb = 0; kb < KB2; kb++) {
        if (kb + 2 < KB2) stage((cur + 2) % 3, kb + 2);
        __builtin_amdgcn_sched_barrier(0);
        compute(cur);
        if (kb + 1 < KB2) {
            if (kb + 2 < KB2) WAIT_VM6();
            else              WAIT_VM0();
            S_BARRIER();
        }
        cur = (cur == 2) ? 0 : cur + 1;
    }

    if (e == NE) {
        // shared expert: every token, weight 1 -> plain f32 stores (covers whole out body)
        #pragma unroll
        for (int m = 0; m < 4; m++) {
            int rbase = wr * 64 + m * 16 + l4 * 4;
            #pragma unroll
            for (int n = 0; n < 4; n++) {
                int col = nb + wc * 64 + n * 16 + l15;
                #pragma unroll
                for (int i = 0; i < 4; i++) {
                    int r = rbase + i;
                    out[(size_t)rows[r] * DD + col] = acc[m][n][i] + bv[n];
                }
            }
        }
    } else {
        // expert tile: weighted bf16 partial into its slot row (no races, no atomics)
        #pragma unroll
        for (int m = 0; m < 4; m++) {
            int rbase = wr * 64 + m * 16 + l4 * 4;
            #pragma unroll
            for (int n = 0; n < 4; n++) {
                int col = nb + wc * 64 + n * 16 + l15;
                #pragma unroll
                for (int i = 0; i < 4; i++) {
                    int r = rbase + i;
                    if (r < acount)
                        yslot[(size_t)(a0 + r) * DD + col] = bfr(wts[r] * (acc[m][n][i] + bv[n]));
                }
            }
        }
    }
}

// out[t,:] += sum_k yslot[sidx[t,k],:]
__global__ __launch_bounds__(256) void k_combine(
    const unsigned short* __restrict__ yslot, const int* __restrict__ sidx,
    float* __restrict__ out)
{
    const int t = blockIdx.x;
    const int s0 = sidx[t * 3 + 0], s1 = sidx[t * 3 + 1], s2 = sidx[t * 3 + 2];
    const int d = threadIdx.x * 4;
    float* o = out + (size_t)t * DD + d;
    float4 v = *(float4*)o;
    ushort4 a = *(const ushort4*)(yslot + (size_t)s0 * DD + d);
    ushort4 b = *(const ushort4*)(yslot + (size_t)s1 * DD + d);
    ushort4 c = *(const ushort4*)(yslot + (size_t)s2 * DD + d);
    v.x += b2f(a.x) + b2f(b.x) + b2f(c.x);
    v.y += b2f(a.y) + b2f(b.y) + b2f(c.y);
    v.z += b2f(a.z) + b2f(b.z) + b2f(c.z);
    v.w += b2f(a.w) + b2f(b.w) + b2f(c.w);
    *(float4*)o = v;
}

extern "C" void kernel_launch(void* const* d_in, const int* in_sizes, int n_in,
                              void* d_out, int out_size, void* d_ws, size_t ws_size,
                              hipStream_t stream)
{
    const float* x    = (const float*)d_in[0];
    const float* gW   = (const float*)d_in[1];
    const float* gb   = (const float*)d_in[2];
    const float* bias = (const float*)d_in[3];
    const float* W1   = (const float*)d_in[4];
    const float* b1   = (const float*)d_in[5];
    const float* W2   = (const float*)d_in[6];
    const float* b2   = (const float*)d_in[7];
    const float* sW1  = (const float*)d_in[8];
    const float* sb1  = (const float*)d_in[9];
    const float* sW2  = (const float*)d_in[10];
    const float* sb2  = (const float*)d_in[11];
    float* out = (float*)d_out;
    float* wsf = (float*)d_ws;
    int*   wsi = (int*)d_ws;

    hipMemsetAsync(d_ws, 0, 2048, stream);   // curs only; out body fully written by k_mm2 shared

    int*   curs   = wsi + WS_CURS;
    int*   counts = wsi + WS_COUNTS;
    float* Psum   = wsf + WS_PSUM;
    int*   offs   = wsi + WS_OFFS;
    int*   toffs  = wsi + WS_TOFFS;
    int*   total  = wsi + WS_TOTAL;
    int*   t2e    = wsi + WS_T2E;
    int*   t2a    = wsi + WS_T2A;
    int*   tokE   = wsi + WS_TOKE;
    float* tokW   = wsf + WS_TOKW;
    int*   ltok   = wsi + WS_LTOK;
    float* lwt    = wsf + WS_LW;
    float* Ppart  = wsf + WS_PPART;
    int*   Cpart  = wsi + WS_CPART;
    int*   sidx   = wsi + WS_SIDX;
    unsigned short* xb  = (unsigned short*)((char*)d_ws + XB_OFF);
    unsigned short* Hb  = (unsigned short*)((char*)d_ws + H_OFF);
    unsigned short* W1b = (unsigned short*)((char*)d_ws + W1B_OFF);
    unsigned short* W2b = (unsigned short*)((char*)d_ws + W2B_OFF);
    unsigned short* yslot = W1b;   // reuse W1b region after k_mm1 is done

    k_cvt_w<<<dim3(HH / 64, DD / 64, NG), 256, 0, stream>>>(W1, sW1, DD, HH, W1b);
    k_cvt_w<<<dim3(DD / 64, HH / 64, NG), 256, 0, stream>>>(W2, sW2, HH, DD, W2b);
    k_gate<<<TT / 4, 256, 0, stream>>>(x, gW, gb, bias, tokE, tokW, Ppart, Cpart, xb);
    k_reduce<<<NE, 256, 0, stream>>>(Ppart, Cpart, counts, Psum);
    k_scan<<<1, 64, 0, stream>>>(counts, Psum, offs, toffs, total, t2e, t2a,
                                 out + (size_t)TT * DD);
    k_scatter<<<TT / 256, 256, 0, stream>>>(tokE, tokW, offs, curs, ltok, lwt, sidx);
    k_mm1<<<NWG1, 512, 0, stream>>>(xb, W1b, b1, sb1, t2e, t2a, offs, total, ltok, Hb);
    k_mm2<<<NWG2, 512, 0, stream>>>(Hb, W2b, b2, sb2, t2e, t2a, offs, total, ltok, lwt,
                                    yslot, out);
    k_combine<<<TT, 256, 0, stream>>>(yslot, sidx, out);
}

// Round 10
// 248.413 us; speedup vs baseline: 1.0749x; 1.0749x over previous
//
#include <hip/hip_runtime.h>
#include <math.h>

#define TT 4096
#define DD 1024
#define HH 768
#define NE 23
#define NG 24          // 23 experts + shared as group 23
#define BM 128
#define BN 128
#define BK 64
#define MAXT 160       // sum ceil(n_e/128) <= 119, + 32 shared tiles = 151
#define KB1 16         // DD/64
#define KB2 12         // HH/64
#define NY1 6          // HH/BN
#define NY2 8          // DD/BN
#define NWG1 (MAXT*NY1)   // 960  (div by 8)
#define NWG2 (MAXT*NY2)   // 1280 (div by 8)
#define CVT1_BLKS 4608    // (HH/64)*(DD/64)*NG = 12*16*24
#define CVT_BLKS  9216    // + (DD/64)*(HH/64)*NG

// ws word offsets (misc, < 512KB)
#define WS_OFFS   576
#define WS_TOTAL  640
#define WS_T2E    672      // tile -> expert/group
#define WS_T2A    832      // tile -> a0
#define WS_TOKE   1024
#define WS_TOKW   13312
#define WS_LTOK   25600
#define WS_LW     41984
#define WS_PPART  58368    // 23*1024 floats
#define WS_CPART  81920    // 23*1024 ints (ends 105472)
#define WS_SIDX   106496   // 12288 ints (ends 118784 < 131072)
// ws byte offsets (big buffers)
#define XB_OFF  ((size_t)524288)      // xb bf16: 4096*1024*2  = 8388608
#define H_OFF   ((size_t)8912896)     // H  bf16: 16384*768*2
#define W1B_OFF ((size_t)34078720)    // W1 blocked bf16: 24*16*768*64*2 = 37748736
                                      //   (reused after mm1 as yslot)
#define W2B_OFF ((size_t)71827456)    // W2 blocked bf16: 24*12*1024*64*2 = 37748736

typedef short bf16x8 __attribute__((ext_vector_type(8)));
typedef float f32x4 __attribute__((ext_vector_type(4)));
typedef unsigned short u16x8 __attribute__((ext_vector_type(8)));

#define S_BARRIER() asm volatile("s_barrier" ::: "memory")
#define WAIT_VM0()  asm volatile("s_waitcnt vmcnt(0)" ::: "memory")

__device__ inline unsigned short bfr(float f) {   // f32 -> bf16 RNE
    unsigned u = __float_as_uint(f);
    u += 0x7fffu + ((u >> 16) & 1u);
    return (unsigned short)(u >> 16);
}
__device__ inline float b2f(unsigned short u) {
    return __uint_as_float((unsigned)u << 16);
}

__device__ __forceinline__ void gl_lds16(const void* g, void* l) {
    __builtin_amdgcn_global_load_lds(
        (const __attribute__((address_space(1))) unsigned int*)g,
        (__attribute__((address_space(3))) unsigned int*)l, 16, 0, 0);
}

// gating + x->bf16 conversion fused (x already staged in LDS)
__global__ __launch_bounds__(256) void k_gate(
    const float* __restrict__ x, const float* __restrict__ gW,
    const float* __restrict__ gb, const float* __restrict__ bias,
    int* __restrict__ tokE, float* __restrict__ tokW,
    float* __restrict__ Ppart, int* __restrict__ Cpart,
    unsigned short* __restrict__ xb)
{
    __shared__ float xs[4][DD];
    __shared__ float gv[4][NE];
    __shared__ float ginvs[4];
    __shared__ int sel[4][3];
    const int tid = threadIdx.x;
    const int t0 = blockIdx.x * 4;
    {
        const float4* src = (const float4*)(x + (size_t)t0 * DD);
        float4* dst = (float4*)&xs[0][0];
        #pragma unroll
        for (int i = 0; i < 4; i++) dst[tid + 256 * i] = src[tid + 256 * i];
    }
    __syncthreads();
    {   // write bf16 copy of the 4 staged tokens
        const float* xf = &xs[0][0];
        unsigned short* xd = xb + (size_t)t0 * DD;
        #pragma unroll
        for (int it = 0; it < 4; it++) {
            int o = it * 1024 + tid * 4;
            ushort4 u = make_ushort4(bfr(xf[o]), bfr(xf[o + 1]), bfr(xf[o + 2]), bfr(xf[o + 3]));
            *(ushort4*)(xd + o) = u;
        }
    }
    const int w = tid >> 6, l = tid & 63;
    const int t = t0 + w;
    if (l < NE) {
        float s0 = 0.f, s1 = 0.f, s2 = 0.f, s3 = 0.f;
        const float* xw = xs[w];
        for (int d = 0; d < DD; d += 4) {
            s0 = fmaf(xw[d + 0], gW[(d + 0) * NE + l], s0);
            s1 = fmaf(xw[d + 1], gW[(d + 1) * NE + l], s1);
            s2 = fmaf(xw[d + 2], gW[(d + 2) * NE + l], s2);
            s3 = fmaf(xw[d + 3], gW[(d + 3) * NE + l], s3);
        }
        float s = (s0 + s1) + (s2 + s3) + gb[l];
        gv[w][l] = 1.f / (1.f + expf(-s));
    }
    __syncthreads();
    if (l == 0) {
        unsigned chosen = 0;
        int be[3]; float bw[3];
        float gsum = 0.f;
        for (int e = 0; e < NE; e++) gsum += gv[w][e];
        #pragma unroll
        for (int k = 0; k < 3; k++) {
            float m = -1e30f; int mi = 0;
            for (int e = 0; e < NE; e++) {
                float kv = gv[w][e] + bias[e];
                if (!((chosen >> e) & 1u) && kv > m) { m = kv; mi = e; }
            }
            chosen |= 1u << mi;
            be[k] = mi; bw[k] = gv[w][mi];
        }
        float inv = 1.f / (bw[0] + bw[1] + bw[2]);
        #pragma unroll
        for (int k = 0; k < 3; k++) {
            tokE[t * 3 + k] = be[k];
            tokW[t * 3 + k] = bw[k] * inv;
            sel[w][k] = be[k];
        }
        ginvs[w] = 1.f / gsum;
    }
    __syncthreads();
    if (tid < NE) {   // per-block partials: NO global atomics
        float p = gv[0][tid] * ginvs[0] + gv[1][tid] * ginvs[1]
                + gv[2][tid] * ginvs[2] + gv[3][tid] * ginvs[3];
        Ppart[tid * 1024 + blockIdx.x] = p;
        int c = 0;
        #pragma unroll
        for (int w2 = 0; w2 < 4; w2++)
            #pragma unroll
            for (int k = 0; k < 3; k++) c += (sel[w2][k] == tid);
        Cpart[tid * 1024 + blockIdx.x] = c;
    }
}

// fused reduce + scan + scatter (single block; LDS atomics for positions)
__global__ __launch_bounds__(256) void k_plan(
    const float* __restrict__ Ppart, const int* __restrict__ Cpart,
    const int* __restrict__ tokE, const float* __restrict__ tokW,
    int* __restrict__ offs, int* __restrict__ total,
    int* __restrict__ t2e, int* __restrict__ t2a,
    int* __restrict__ ltok, float* __restrict__ lw,
    int* __restrict__ sidx, float* __restrict__ outAux)
{
    __shared__ float sps[NE];
    __shared__ int scnt[NE];
    __shared__ int soffs[NG + 1];
    __shared__ int scurs[NE];
    const int tid = threadIdx.x;
    const int wid = tid >> 6, lane = tid & 63;
    if (tid < NE) scurs[tid] = 0;
    for (int e = wid; e < NE; e += 4) {      // wave per expert (round-robin)
        float s = 0.f; int c = 0;
        for (int i = lane; i < 1024; i += 64) {
            s += Ppart[e * 1024 + i];
            c += Cpart[e * 1024 + i];
        }
        #pragma unroll
        for (int off = 32; off >= 1; off >>= 1) {
            s += __shfl_down(s, off, 64);
            c += __shfl_down(c, off, 64);
        }
        if (lane == 0) { sps[e] = s; scnt[e] = c; }
    }
    __syncthreads();
    if (tid == 0) {
        int off = 0, toff = 0;
        for (int e = 0; e < NG; e++) {
            int c = (e < NE) ? scnt[e] : TT;
            soffs[e] = off; offs[e] = off;
            int nt = (c + BM - 1) / BM;
            for (int t = 0; t < nt; t++) {
                t2e[toff + t] = e;
                t2a[toff + t] = off + t * BM;
            }
            off += c; toff += nt;
        }
        soffs[NG] = off; offs[NG] = off;
        *total = toff;
        float aux = 0.f;
        for (int e = 0; e < NE; e++) {
            float P = sps[e] / (float)TT;
            float F = (float)NE * (float)scnt[e] / (float)(3 * TT);
            aux += P * F;
        }
        outAux[0] = aux;
        for (int e = 0; e < NE; e++) outAux[1 + e] = (float)scnt[e];
    }
    __syncthreads();
    for (int t = tid; t < TT; t += 256) {    // scatter (LDS-atomic positions)
        #pragma unroll
        for (int k = 0; k < 3; k++) {
            int e = tokE[t * 3 + k];
            int pos = atomicAdd(&scurs[e], 1);
            int idx = soffs[e] + pos;
            ltok[idx] = t; lw[idx] = tokW[t * 3 + k];
            sidx[t * 3 + k] = idx;
        }
        ltok[3 * TT + t] = t;
        lw[3 * TT + t] = 1.f;
    }
}

// W1 and W2 conversion fused in one launch.
// dst[((e*KBt+kb)*N + n)*64 + p*8 + i] = bf16(W[kb*64 + j*8 + i][n]), p = j ^ (n&7)
__global__ __launch_bounds__(256) void k_cvt_all(
    const float* __restrict__ W1, const float* __restrict__ sW1,
    const float* __restrict__ W2, const float* __restrict__ sW2,
    unsigned short* __restrict__ W1b, unsigned short* __restrict__ W2b)
{
    __shared__ unsigned short Ls[64][66];
    int id = blockIdx.x;
    const float* src; unsigned short* dst;
    int N, kb, n0, KBt, e;
    if (id < CVT1_BLKS) {          // W1: K=DD, N=HH
        N = HH; KBt = 16;
        n0 = (id % 12) * 64; kb = (id / 12) % 16; e = id / 192;
        src = (e < NE) ? (W1 + (size_t)e * DD * HH) : sW1;
        dst = W1b;
    } else {                       // W2: K=HH, N=DD
        id -= CVT1_BLKS;
        N = DD; KBt = 12;
        n0 = (id % 16) * 64; kb = (id / 16) % 12; e = id / 192;
        src = (e < NE) ? (W2 + (size_t)e * HH * DD) : sW2;
        dst = W2b;
    }
    const int tid = threadIdx.x;
    const int c = (tid & 15) * 4, r0 = tid >> 4;
    #pragma unroll
    for (int pass = 0; pass < 4; pass++) {
        int row = pass * 16 + r0;
        float4 v = *(const float4*)(src + (size_t)(kb * 64 + row) * N + n0 + c);
        ushort4 u = make_ushort4(bfr(v.x), bfr(v.y), bfr(v.z), bfr(v.w));
        *(ushort4*)&Ls[row][c] = u;
    }
    __syncthreads();
    unsigned short* dbase = dst + ((size_t)(e * KBt + kb) * N + n0) * 64;
    #pragma unroll
    for (int half = 0; half < 2; half++) {
        int g = half * 256 + tid;
        int n = g >> 3, p = g & 7;
        int j = p ^ (n & 7);
        u16x8 u;
        #pragma unroll
        for (int i = 0; i < 8; i++) u[i] = Ls[j * 8 + i][n];
        *(u16x8*)(dbase + n * 64 + p * 8) = u;   // consecutive tid -> consecutive 16B
    }
}

// grouped bf16-MFMA GEMM1 + fast GeLU; T3-minimum 2-phase: stage-before-compute,
// ONE vmcnt(0)+barrier per K-step  (r8 structure, best measured)
__global__ __launch_bounds__(256) void k_mm1(
    const unsigned short* __restrict__ xb, const unsigned short* __restrict__ W1b,
    const float* __restrict__ b1, const float* __restrict__ sb1,
    const int* __restrict__ t2e, const int* __restrict__ t2a,
    const int* __restrict__ offs, const int* __restrict__ total,
    const int* __restrict__ ltok, unsigned short* __restrict__ H)
{
    const int id = blockIdx.x;
    const int wg = (id & 7) * (NWG1 / 8) + (id >> 3);   // XCD-aware bijective swizzle
    const int ns = wg / MAXT;
    const int tb = wg % MAXT;
    if (tb >= *total) return;
    const int e = t2e[tb];
    const int a0 = t2a[tb];
    const int acount = min(offs[e + 1] - a0, BM);
    const float* bb = (e < NE) ? (b1 + e * HH) : sb1;
    const int nb = ns * BN;

    __shared__ unsigned short As[2][BM * BK];
    __shared__ unsigned short Bs[2][BN * BK];
    __shared__ int rows[BM];
    const int tid = threadIdx.x;
    if (tid < BM) rows[tid] = ltok[a0 + min(tid, acount - 1)];  // clamped gather
    __syncthreads();

    const int wid = tid >> 6, lane = tid & 63;
    const int wr = wid >> 1, wc = wid & 1;
    const int l15 = lane & 15, l4 = lane >> 4;

    float bv[4];
    #pragma unroll
    for (int n = 0; n < 4; n++) bv[n] = bb[nb + wc * 64 + n * 16 + l15];

    f32x4 acc[4][4];
    #pragma unroll
    for (int m = 0; m < 4; m++)
        #pragma unroll
        for (int n = 0; n < 4; n++) acc[m][n] = (f32x4){0.f, 0.f, 0.f, 0.f};

    const unsigned short* aSrc[4];
    int Goff[4];
    #pragma unroll
    for (int c = 0; c < 4; c++) {
        int G = (wid * 4 + c) * 64 + lane;
        int row = G >> 3, j = G & 7;
        aSrc[c] = xb + (size_t)rows[row] * DD + ((j ^ (row & 7)) << 3);
        Goff[c] = G * 8;
    }
    const unsigned short* wbase = W1b + ((size_t)e * KB1 * HH + nb) * 64;

    auto stage = [&](int buf, int kb) {   // 8 VMEM ops per thread
        #pragma unroll
        for (int c = 0; c < 4; c++)
            gl_lds16(aSrc[c] + kb * 64, &As[buf][Goff[c]]);
        const unsigned short* wb = wbase + (size_t)kb * (HH * 64);
        #pragma unroll
        for (int c = 0; c < 4; c++)
            gl_lds16(wb + Goff[c], &Bs[buf][Goff[c]]);
    };
    auto compute = [&](int buf) {
        #pragma unroll
        for (int kh = 0; kh < 2; kh++) {
            bf16x8 af[4], bf[4];
            #pragma unroll
            for (int f = 0; f < 4; f++) {
                int ar = wr * 64 + f * 16 + l15;
                int br = wc * 64 + f * 16 + l15;
                int pg = (kh << 2) + l4;
                af[f] = *(const bf16x8*)&As[buf][ar * 64 + ((pg ^ (ar & 7)) << 3)];
                bf[f] = *(const bf16x8*)&Bs[buf][br * 64 + ((pg ^ (br & 7)) << 3)];
            }
            #pragma unroll
            for (int m = 0; m < 4; m++)
                #pragma unroll
                for (int n = 0; n < 4; n++)
                    acc[m][n] = __builtin_amdgcn_mfma_f32_16x16x32_bf16(af[m], bf[n], acc[m][n], 0, 0, 0);
        }
    };

    stage(0, 0);
    WAIT_VM0();
    S_BARRIER();
    int cur = 0;
    #pragma unroll 1
    for (int kb = 0; kb < KB1; kb++) {
        if (kb + 1 < KB1) stage(cur ^ 1, kb + 1);   // issue next-tile loads FIRST
        __builtin_amdgcn_sched_barrier(0);          // pin issue order
        compute(cur);                               // MFMA hides the load latency
        if (kb + 1 < KB1) {
            WAIT_VM0();
            S_BARRIER();
            cur ^= 1;
        }
    }

    #pragma unroll
    for (int m = 0; m < 4; m++) {
        int rbase = wr * 64 + m * 16 + l4 * 4;
        #pragma unroll
        for (int n = 0; n < 4; n++) {
            int col = nb + wc * 64 + n * 16 + l15;
            #pragma unroll
            for (int i = 0; i < 4; i++) {
                int r = rbase + i;
                if (r < acount) {
                    float v = acc[m][n][i] + bv[n];
                    float u = v + 0.044715f * v * v * v;
                    float g = v / (1.f + __expf(-1.5957691216f * u));  // tanh-gelu
                    H[(size_t)(a0 + r) * HH + col] = bfr(g);
                }
            }
        }
    }
}

// grouped bf16-MFMA GEMM2; T3-minimum 2-phase (r8 structure).
// expert tiles -> weighted bf16 slot stores; shared tile -> plain f32 out stores
__global__ __launch_bounds__(256) void k_mm2(
    const unsigned short* __restrict__ H, const unsigned short* __restrict__ W2b,
    const float* __restrict__ b2, const float* __restrict__ sb2,
    const int* __restrict__ t2e, const int* __restrict__ t2a,
    const int* __restrict__ offs, const int* __restrict__ total,
    const int* __restrict__ ltok, const float* __restrict__ lw,
    unsigned short* __restrict__ yslot, float* __restrict__ out)
{
    const int id = blockIdx.x;
    const int wg = (id & 7) * (NWG2 / 8) + (id >> 3);
    const int ns = wg / MAXT;
    const int tb = wg % MAXT;
    if (tb >= *total) return;
    const int e = t2e[tb];
    const int a0 = t2a[tb];
    const int acount = min(offs[e + 1] - a0, BM);
    const float* bb = (e < NE) ? (b2 + e * DD) : sb2;
    const int nb = ns * BN;

    __shared__ unsigned short As[2][BM * BK];
    __shared__ unsigned short Bs[2][BN * BK];
    __shared__ int rows[BM];
    __shared__ float wts[BM];
    const int tid = threadIdx.x;
    if (tid < BM) {
        rows[tid] = (tid < acount) ? ltok[a0 + tid] : -1;
        wts[tid]  = (tid < acount) ? lw[a0 + tid] : 0.f;
    }
    __syncthreads();

    const int wid = tid >> 6, lane = tid & 63;
    const int wr = wid >> 1, wc = wid & 1;
    const int l15 = lane & 15, l4 = lane >> 4;

    float bv[4];
    #pragma unroll
    for (int n = 0; n < 4; n++) bv[n] = bb[nb + wc * 64 + n * 16 + l15];

    f32x4 acc[4][4];
    #pragma unroll
    for (int m = 0; m < 4; m++)
        #pragma unroll
        for (int n = 0; n < 4; n++) acc[m][n] = (f32x4){0.f, 0.f, 0.f, 0.f};

    const unsigned short* aSrc[4];
    int Goff[4];
    #pragma unroll
    for (int c = 0; c < 4; c++) {
        int G = (wid * 4 + c) * 64 + lane;
        int row = G >> 3, j = G & 7;
        aSrc[c] = H + (size_t)(a0 + row) * HH + ((j ^ (row & 7)) << 3);  // contiguous rows
        Goff[c] = G * 8;
    }
    const unsigned short* wbase = W2b + ((size_t)e * KB2 * DD + nb) * 64;

    auto stage = [&](int buf, int kb) {
        #pragma unroll
        for (int c = 0; c < 4; c++)
            gl_lds16(aSrc[c] + kb * 64, &As[buf][Goff[c]]);
        const unsigned short* wb = wbase + (size_t)kb * (DD * 64);
        #pragma unroll
        for (int c = 0; c < 4; c++)
            gl_lds16(wb + Goff[c], &Bs[buf][Goff[c]]);
    };
    auto compute = [&](int buf) {
        #pragma unroll
        for (int kh = 0; kh < 2; kh++) {
            bf16x8 af[4], bf[4];
            #pragma unroll
            for (int f = 0; f < 4; f++) {
                int ar = wr * 64 + f * 16 + l15;
                int br = wc * 64 + f * 16 + l15;
                int pg = (kh << 2) + l4;
                af[f] = *(const bf16x8*)&As[buf][ar * 64 + ((pg ^ (ar & 7)) << 3)];
                bf[f] = *(const bf16x8*)&Bs[buf][br * 64 + ((pg ^ (br & 7)) << 3)];
            }
            #pragma unroll
            for (int m = 0; m < 4; m++)
                #pragma unroll
                for (int n = 0; n < 4; n++)
                    acc[m][n] = __builtin_amdgcn_mfma_f32_16x16x32_bf16(af[m], bf[n], acc[m][n], 0, 0, 0);
        }
    };

    stage(0, 0);
    WAIT_VM0();
    S_BARRIER();
    int cur = 0;
    #pragma unroll 1
    for (int kb = 0; kb < KB2; kb++) {
        if (kb + 1 < KB2) stage(cur ^ 1, kb + 1);
        __builtin_amdgcn_sched_barrier(0);
        compute(cur);
        if (kb + 1 < KB2) {
            WAIT_VM0();
            S_BARRIER();
            cur ^= 1;
        }
    }

    if (e == NE) {
        // shared expert: every token, weight 1 -> plain f32 stores (covers whole out body)
        #pragma unroll
        for (int m = 0; m < 4; m++) {
            int rbase = wr * 64 + m * 16 + l4 * 4;
            #pragma unroll
            for (int n = 0; n < 4; n++) {
                int col = nb + wc * 64 + n * 16 + l15;
                #pragma unroll
                for (int i = 0; i < 4; i++) {
                    int r = rbase + i;
                    out[(size_t)rows[r] * DD + col] = acc[m][n][i] + bv[n];
                }
            }
        }
    } else {
        // expert tile: weighted bf16 partial into its slot row (no races, no atomics)
        #pragma unroll
        for (int m = 0; m < 4; m++) {
            int rbase = wr * 64 + m * 16 + l4 * 4;
            #pragma unroll
            for (int n = 0; n < 4; n++) {
                int col = nb + wc * 64 + n * 16 + l15;
                #pragma unroll
                for (int i = 0; i < 4; i++) {
                    int r = rbase + i;
                    if (r < acount)
                        yslot[(size_t)(a0 + r) * DD + col] = bfr(wts[r] * (acc[m][n][i] + bv[n]));
                }
            }
        }
    }
}

// out[t,:] += sum_k yslot[sidx[t,k],:]
__global__ __launch_bounds__(256) void k_combine(
    const unsigned short* __restrict__ yslot, const int* __restrict__ sidx,
    float* __restrict__ out)
{
    const int t = blockIdx.x;
    const int s0 = sidx[t * 3 + 0], s1 = sidx[t * 3 + 1], s2 = sidx[t * 3 + 2];
    const int d = threadIdx.x * 4;
    float* o = out + (size_t)t * DD + d;
    float4 v = *(float4*)o;
    ushort4 a = *(const ushort4*)(yslot + (size_t)s0 * DD + d);
    ushort4 b = *(const ushort4*)(yslot + (size_t)s1 * DD + d);
    ushort4 c = *(const ushort4*)(yslot + (size_t)s2 * DD + d);
    v.x += b2f(a.x) + b2f(b.x) + b2f(c.x);
    v.y += b2f(a.y) + b2f(b.y) + b2f(c.y);
    v.z += b2f(a.z) + b2f(b.z) + b2f(c.z);
    v.w += b2f(a.w) + b2f(b.w) + b2f(c.w);
    *(float4*)o = v;
}

extern "C" void kernel_launch(void* const* d_in, const int* in_sizes, int n_in,
                              void* d_out, int out_size, void* d_ws, size_t ws_size,
                              hipStream_t stream)
{
    const float* x    = (const float*)d_in[0];
    const float* gW   = (const float*)d_in[1];
    const float* gb   = (const float*)d_in[2];
    const float* bias = (const float*)d_in[3];
    const float* W1   = (const float*)d_in[4];
    const float* b1   = (const float*)d_in[5];
    const float* W2   = (const float*)d_in[6];
    const float* b2   = (const float*)d_in[7];
    const float* sW1  = (const float*)d_in[8];
    const float* sb1  = (const float*)d_in[9];
    const float* sW2  = (const float*)d_in[10];
    const float* sb2  = (const float*)d_in[11];
    float* out = (float*)d_out;
    float* wsf = (float*)d_ws;
    int*   wsi = (int*)d_ws;

    int*   offs   = wsi + WS_OFFS;
    int*   total  = wsi + WS_TOTAL;
    int*   t2e    = wsi + WS_T2E;
    int*   t2a    = wsi + WS_T2A;
    int*   tokE   = wsi + WS_TOKE;
    float* tokW   = wsf + WS_TOKW;
    int*   ltok   = wsi + WS_LTOK;
    float* lwt    = wsf + WS_LW;
    float* Ppart  = wsf + WS_PPART;
    int*   Cpart  = wsi + WS_CPART;
    int*   sidx   = wsi + WS_SIDX;
    unsigned short* xb  = (unsigned short*)((char*)d_ws + XB_OFF);
    unsigned short* Hb  = (unsigned short*)((char*)d_ws + H_OFF);
    unsigned short* W1b = (unsigned short*)((char*)d_ws + W1B_OFF);
    unsigned short* W2b = (unsigned short*)((char*)d_ws + W2B_OFF);
    unsigned short* yslot = W1b;   // reuse W1b region after k_mm1 is done

    k_cvt_all<<<CVT_BLKS, 256, 0, stream>>>(W1, sW1, W2, sW2, W1b, W2b);
    k_gate<<<TT / 4, 256, 0, stream>>>(x, gW, gb, bias, tokE, tokW, Ppart, Cpart, xb);
    k_plan<<<1, 256, 0, stream>>>(Ppart, Cpart, tokE, tokW, offs, total, t2e, t2a,
                                  ltok, lwt, sidx, out + (size_t)TT * DD);
    k_mm1<<<NWG1, 256, 0, stream>>>(xb, W1b, b1, sb1, t2e, t2a, offs, total, ltok, Hb);
    k_mm2<<<NWG2, 256, 0, stream>>>(Hb, W2b, b2, sb2, t2e, t2a, offs, total, ltok, lwt,
                                    yslot, out);
    k_combine<<<TT, 256, 0, stream>>>(yslot, sidx, out);
}

// Round 11
// 225.483 us; speedup vs baseline: 1.1842x; 1.1017x over previous
//
#include <hip/hip_runtime.h>
#include <math.h>

#define TT 4096
#define DD 1024
#define HH 768
#define NE 23
#define NG 24          // 23 experts + shared as group 23
#define BM 128
#define BN 128
#define BK 64
#define MAXT 160       // sum ceil(n_e/128) <= 119, + 32 shared tiles = 151
#define KB1 16         // DD/64
#define KB2 12         // HH/64
#define NY1 6          // HH/BN
#define NY2 8          // DD/BN
#define NWG1 (MAXT*NY1)   // 960  (div by 8)
#define NWG2 (MAXT*NY2)   // 1280 (div by 8)
#define CVT1_BLKS 2304    // 12 nblk * 8 kpair * 24 e
#define CVT_TOT   4608    // + 16 nblk * 6 kpair * 24 e
#define GATE_BLKS 1024    // TT/4

// ws word offsets (misc, < 512KB)
#define WS_CURS   0        // 23*16 ints (1 cache line per expert)
#define WS_OFFS   576
#define WS_TOTAL  640
#define WS_T2E    672      // tile -> expert/group
#define WS_T2A    832      // tile -> a0
#define WS_TOKE   1024
#define WS_TOKW   13312
#define WS_LTOK   25600
#define WS_LW     41984
#define WS_PPART  58368    // 23*1024 floats
#define WS_CPART  81920    // 23*1024 ints (ends 105472)
#define WS_SIDX   106496   // 12288 ints (ends 118784 < 131072)
// ws byte offsets (big buffers)
#define XB_OFF  ((size_t)524288)      // xb bf16: 4096*1024*2  = 8388608
#define H_OFF   ((size_t)8912896)     // H  bf16: 16384*768*2
#define W1B_OFF ((size_t)34078720)    // W1 blocked bf16: 24*16*768*64*2 = 37748736
                                      //   (reused after mm1 as yslot)
#define W2B_OFF ((size_t)71827456)    // W2 blocked bf16: 24*12*1024*64*2 = 37748736

typedef short bf16x8 __attribute__((ext_vector_type(8)));
typedef float f32x4 __attribute__((ext_vector_type(4)));

#define S_BARRIER() asm volatile("s_barrier" ::: "memory")
#define WAIT_VM0()  asm volatile("s_waitcnt vmcnt(0)" ::: "memory")

__device__ inline unsigned short bfr(float f) {   // f32 -> bf16 RNE
    unsigned u = __float_as_uint(f);
    u += 0x7fffu + ((u >> 16) & 1u);
    return (unsigned short)(u >> 16);
}
__device__ inline unsigned bfr2(float lo, float hi) {  // pack 2 bf16 into dword
    return (unsigned)bfr(lo) | ((unsigned)bfr(hi) << 16);
}
__device__ inline float b2f(unsigned short u) {
    return __uint_as_float((unsigned)u << 16);
}

__device__ __forceinline__ void gl_lds16(const void* g, void* l) {
    __builtin_amdgcn_global_load_lds(
        (const __attribute__((address_space(1))) unsigned int*)g,
        (__attribute__((address_space(3))) unsigned int*)l, 16, 0, 0);
}

// ONE launch: blocks [0, CVT_TOT) convert W1/W2 (2 k-tiles each, dword-pair
// transpose, XOR swizzle baked in); blocks [CVT_TOT, CVT_TOT+GATE_BLKS) do
// gating + x->bf16. Independent work fused so gate rides under cvt's BW time.
__global__ __launch_bounds__(256) void k_gatecvt(
    const float* __restrict__ x, const float* __restrict__ gW,
    const float* __restrict__ gb, const float* __restrict__ bias,
    const float* __restrict__ W1, const float* __restrict__ sW1,
    const float* __restrict__ W2, const float* __restrict__ sW2,
    int* __restrict__ tokE, float* __restrict__ tokW,
    float* __restrict__ Ppart, int* __restrict__ Cpart,
    unsigned short* __restrict__ xb,
    unsigned short* __restrict__ W1b, unsigned short* __restrict__ W2b)
{
    __shared__ __align__(16) char smem[16896];
    const int tid = threadIdx.x;

    if (blockIdx.x < CVT_TOT) {
        // ---------------- weight conversion path ----------------
        int id = blockIdx.x;
        const float* src; unsigned short* dst;
        int N, kb0, n0, KBt, e;
        if (id < CVT1_BLKS) {              // W1: K=DD, N=HH
            N = HH; KBt = KB1;
            n0 = (id % 12) * 64; kb0 = ((id / 12) % 8) * 2; e = id / 96;
            src = (e < NE) ? (W1 + (size_t)e * DD * HH) : sW1;
            dst = W1b;
        } else {                           // W2: K=HH, N=DD
            id -= CVT1_BLKS;
            N = DD; KBt = KB2;
            n0 = (id % 16) * 64; kb0 = ((id / 16) % 6) * 2; e = id / 96;
            src = (e < NE) ? (W2 + (size_t)e * HH * DD) : sW2;
            dst = W2b;
        }
        // Ls[t][row2][col] : uint = bf16(row 2*row2) | bf16(row 2*row2+1)<<16
        unsigned (*Ls)[32][65] = (unsigned (*)[32][65])smem;
        const int c = (tid & 15) * 4, r2l = tid >> 4;   // r2l in 0..15
        #pragma unroll
        for (int t = 0; t < 2; t++) {
            const float* tsrc = src + (size_t)(kb0 + t) * 64 * N + n0;
            #pragma unroll
            for (int pass = 0; pass < 2; pass++) {
                int row2 = pass * 16 + r2l;
                float4 v0 = *(const float4*)(tsrc + (size_t)(2 * row2) * N + c);
                float4 v1 = *(const float4*)(tsrc + (size_t)(2 * row2 + 1) * N + c);
                uint4 o;
                o.x = bfr2(v0.x, v1.x); o.y = bfr2(v0.y, v1.y);
                o.z = bfr2(v0.z, v1.z); o.w = bfr2(v0.w, v1.w);
                *(uint4*)&Ls[t][row2][c] = o;
            }
        }
        __syncthreads();
        #pragma unroll
        for (int t = 0; t < 2; t++) {
            unsigned short* dbase = dst + ((size_t)(e * KBt + kb0 + t) * N + n0) * 64;
            #pragma unroll
            for (int half = 0; half < 2; half++) {
                int g = half * 256 + tid;
                int n = g >> 3, p = g & 7;
                int j4 = (p ^ (n & 7)) * 4;
                uint4 o;
                o.x = Ls[t][j4 + 0][n]; o.y = Ls[t][j4 + 1][n];
                o.z = Ls[t][j4 + 2][n]; o.w = Ls[t][j4 + 3][n];
                *(uint4*)(dbase + n * 64 + p * 8) = o;  // consecutive tid -> consecutive 16B
            }
        }
        return;
    }

    // ---------------- gating path ----------------
    float (*xs)[DD] = (float (*)[DD])smem;                   // 16384 B
    float (*gv)[NE] = (float (*)[NE])(smem + 16384);         // 368 B
    float* ginvs    = (float*)(smem + 16768);                // 16 B
    int (*sel)[3]   = (int (*)[3])(smem + 16784);            // 48 B
    const int bid = blockIdx.x - CVT_TOT;
    const int t0 = bid * 4;
    {
        const float4* srcx = (const float4*)(x + (size_t)t0 * DD);
        float4* dstx = (float4*)&xs[0][0];
        #pragma unroll
        for (int i = 0; i < 4; i++) dstx[tid + 256 * i] = srcx[tid + 256 * i];
    }
    __syncthreads();
    {   // write bf16 copy of the 4 staged tokens
        const float* xf = &xs[0][0];
        unsigned short* xd = xb + (size_t)t0 * DD;
        #pragma unroll
        for (int it = 0; it < 4; it++) {
            int o = it * 1024 + tid * 4;
            ushort4 u = make_ushort4(bfr(xf[o]), bfr(xf[o + 1]), bfr(xf[o + 2]), bfr(xf[o + 3]));
            *(ushort4*)(xd + o) = u;
        }
    }
    const int w = tid >> 6, l = tid & 63;
    const int t = t0 + w;
    if (l < NE) {
        float s0 = 0.f, s1 = 0.f, s2 = 0.f, s3 = 0.f;
        const float* xw = xs[w];
        for (int d = 0; d < DD; d += 4) {
            s0 = fmaf(xw[d + 0], gW[(d + 0) * NE + l], s0);
            s1 = fmaf(xw[d + 1], gW[(d + 1) * NE + l], s1);
            s2 = fmaf(xw[d + 2], gW[(d + 2) * NE + l], s2);
            s3 = fmaf(xw[d + 3], gW[(d + 3) * NE + l], s3);
        }
        float s = (s0 + s1) + (s2 + s3) + gb[l];
        gv[w][l] = 1.f / (1.f + expf(-s));
    }
    __syncthreads();
    if (l == 0) {
        unsigned chosen = 0;
        int be[3]; float bw[3];
        float gsum = 0.f;
        for (int e = 0; e < NE; e++) gsum += gv[w][e];
        #pragma unroll
        for (int k = 0; k < 3; k++) {
            float m = -1e30f; int mi = 0;
            for (int e = 0; e < NE; e++) {
                float kv = gv[w][e] + bias[e];
                if (!((chosen >> e) & 1u) && kv > m) { m = kv; mi = e; }
            }
            chosen |= 1u << mi;
            be[k] = mi; bw[k] = gv[w][mi];
        }
        float inv = 1.f / (bw[0] + bw[1] + bw[2]);
        #pragma unroll
        for (int k = 0; k < 3; k++) {
            tokE[t * 3 + k] = be[k];
            tokW[t * 3 + k] = bw[k] * inv;
            sel[w][k] = be[k];
        }
        ginvs[w] = 1.f / gsum;
    }
    __syncthreads();
    if (tid < NE) {   // per-block partials: NO global atomics
        float p = gv[0][tid] * ginvs[0] + gv[1][tid] * ginvs[1]
                + gv[2][tid] * ginvs[2] + gv[3][tid] * ginvs[3];
        Ppart[tid * 1024 + bid] = p;
        int c = 0;
        #pragma unroll
        for (int w2 = 0; w2 < 4; w2++)
            #pragma unroll
            for (int k = 0; k < 3; k++) c += (sel[w2][k] == tid);
        Cpart[tid * 1024 + bid] = c;
    }
}

__global__ __launch_bounds__(256) void k_reduce(
    const float* __restrict__ Ppart, const int* __restrict__ Cpart,
    int* __restrict__ counts, float* __restrict__ Psum)
{
    const int e = blockIdx.x;
    const int tid = threadIdx.x;
    float s = 0.f; int c = 0;
    for (int i = tid; i < 1024; i += 256) {
        s += Ppart[e * 1024 + i];
        c += Cpart[e * 1024 + i];
    }
    #pragma unroll
    for (int off = 32; off >= 1; off >>= 1) {
        s += __shfl_down(s, off, 64);
        c += __shfl_down(c, off, 64);
    }
    __shared__ float ss[4]; __shared__ int sc[4];
    if ((tid & 63) == 0) { ss[tid >> 6] = s; sc[tid >> 6] = c; }
    __syncthreads();
    if (tid == 0) {
        Psum[e] = ss[0] + ss[1] + ss[2] + ss[3];
        counts[e] = sc[0] + sc[1] + sc[2] + sc[3];
    }
}

// counts (WS area reuse): stash counts/Psum in curs region tail? use dedicated:
__global__ void k_scan(const int* __restrict__ counts, const float* __restrict__ Psum,
                       int* __restrict__ offs, int* __restrict__ total,
                       int* __restrict__ t2e, int* __restrict__ t2a,
                       int* __restrict__ curs, float* __restrict__ outAux)
{
    const int tid = threadIdx.x;
    for (int i = tid; i < NE * 16; i += 256) curs[i] = 0;   // replaces memset
    if (tid != 0) return;
    int off = 0, toff = 0;
    for (int e = 0; e < NG; e++) {
        int c = (e < NE) ? counts[e] : TT;
        offs[e] = off;
        int nt = (c + BM - 1) / BM;
        for (int t = 0; t < nt; t++) {
            t2e[toff + t] = e;
            t2a[toff + t] = off + t * BM;
        }
        off += c; toff += nt;
    }
    offs[NG] = off;
    *total = toff;
    float aux = 0.f;
    for (int e = 0; e < NE; e++) {
        float P = Psum[e] / (float)TT;
        float F = (float)NE * (float)counts[e] / (float)(3 * TT);
        aux += P * F;
    }
    outAux[0] = aux;
    for (int e = 0; e < NE; e++) outAux[1 + e] = (float)counts[e];
}

__global__ void k_scatter(const int* __restrict__ tokE, const float* __restrict__ tokW,
                          const int* __restrict__ offs, int* __restrict__ curs,
                          int* __restrict__ ltok, float* __restrict__ lw,
                          int* __restrict__ sidx)
{
    int t = blockIdx.x * 256 + threadIdx.x;
    if (t >= TT) return;
    #pragma unroll
    for (int k = 0; k < 3; k++) {
        int e = tokE[t * 3 + k];
        int pos = atomicAdd(&curs[e * 16], 1);   // 1 cache line per expert counter
        int idx = offs[e] + pos;
        ltok[idx] = t; lw[idx] = tokW[t * 3 + k];
        sidx[t * 3 + k] = idx;
    }
    ltok[3 * TT + t] = t;
    lw[3 * TT + t] = 1.f;
}

// grouped bf16-MFMA GEMM1 + fast GeLU; T3-minimum 2-phase (r8 structure, best)
__global__ __launch_bounds__(256) void k_mm1(
    const unsigned short* __restrict__ xb, const unsigned short* __restrict__ W1b,
    const float* __restrict__ b1, const float* __restrict__ sb1,
    const int* __restrict__ t2e, const int* __restrict__ t2a,
    const int* __restrict__ offs, const int* __restrict__ total,
    const int* __restrict__ ltok, unsigned short* __restrict__ H)
{
    const int id = blockIdx.x;
    const int wg = (id & 7) * (NWG1 / 8) + (id >> 3);   // XCD-aware bijective swizzle
    const int ns = wg / MAXT;
    const int tb = wg % MAXT;
    if (tb >= *total) return;
    const int e = t2e[tb];
    const int a0 = t2a[tb];
    const int acount = min(offs[e + 1] - a0, BM);
    const float* bb = (e < NE) ? (b1 + e * HH) : sb1;
    const int nb = ns * BN;

    __shared__ unsigned short As[2][BM * BK];
    __shared__ unsigned short Bs[2][BN * BK];
    __shared__ int rows[BM];
    const int tid = threadIdx.x;
    if (tid < BM) rows[tid] = ltok[a0 + min(tid, acount - 1)];  // clamped gather
    __syncthreads();

    const int wid = tid >> 6, lane = tid & 63;
    const int wr = wid >> 1, wc = wid & 1;
    const int l15 = lane & 15, l4 = lane >> 4;

    float bv[4];
    #pragma unroll
    for (int n = 0; n < 4; n++) bv[n] = bb[nb + wc * 64 + n * 16 + l15];

    f32x4 acc[4][4];
    #pragma unroll
    for (int m = 0; m < 4; m++)
        #pragma unroll
        for (int n = 0; n < 4; n++) acc[m][n] = (f32x4){0.f, 0.f, 0.f, 0.f};

    const unsigned short* aSrc[4];
    int Goff[4];
    #pragma unroll
    for (int c = 0; c < 4; c++) {
        int G = (wid * 4 + c) * 64 + lane;
        int row = G >> 3, j = G & 7;
        aSrc[c] = xb + (size_t)rows[row] * DD + ((j ^ (row & 7)) << 3);
        Goff[c] = G * 8;
    }
    const unsigned short* wbase = W1b + ((size_t)e * KB1 * HH + nb) * 64;

    auto stage = [&](int buf, int kb) {   // 8 VMEM ops per thread
        #pragma unroll
        for (int c = 0; c < 4; c++)
            gl_lds16(aSrc[c] + kb * 64, &As[buf][Goff[c]]);
        const unsigned short* wb = wbase + (size_t)kb * (HH * 64);
        #pragma unroll
        for (int c = 0; c < 4; c++)
            gl_lds16(wb + Goff[c], &Bs[buf][Goff[c]]);
    };
    auto compute = [&](int buf) {
        #pragma unroll
        for (int kh = 0; kh < 2; kh++) {
            bf16x8 af[4], bf[4];
            #pragma unroll
            for (int f = 0; f < 4; f++) {
                int ar = wr * 64 + f * 16 + l15;
                int br = wc * 64 + f * 16 + l15;
                int pg = (kh << 2) + l4;
                af[f] = *(const bf16x8*)&As[buf][ar * 64 + ((pg ^ (ar & 7)) << 3)];
                bf[f] = *(const bf16x8*)&Bs[buf][br * 64 + ((pg ^ (br & 7)) << 3)];
            }
            #pragma unroll
            for (int m = 0; m < 4; m++)
                #pragma unroll
                for (int n = 0; n < 4; n++)
                    acc[m][n] = __builtin_amdgcn_mfma_f32_16x16x32_bf16(af[m], bf[n], acc[m][n], 0, 0, 0);
        }
    };

    stage(0, 0);
    WAIT_VM0();
    S_BARRIER();
    int cur = 0;
    #pragma unroll 1
    for (int kb = 0; kb < KB1; kb++) {
        if (kb + 1 < KB1) stage(cur ^ 1, kb + 1);   // issue next-tile loads FIRST
        __builtin_amdgcn_sched_barrier(0);          // pin issue order
        compute(cur);                               // MFMA hides the load latency
        if (kb + 1 < KB1) {
            WAIT_VM0();
            S_BARRIER();
            cur ^= 1;
        }
    }

    #pragma unroll
    for (int m = 0; m < 4; m++) {
        int rbase = wr * 64 + m * 16 + l4 * 4;
        #pragma unroll
        for (int n = 0; n < 4; n++) {
            int col = nb + wc * 64 + n * 16 + l15;
            #pragma unroll
            for (int i = 0; i < 4; i++) {
                int r = rbase + i;
                if (r < acount) {
                    float v = acc[m][n][i] + bv[n];
                    float u = v + 0.044715f * v * v * v;
                    float g = v / (1.f + __expf(-1.5957691216f * u));  // tanh-gelu
                    H[(size_t)(a0 + r) * HH + col] = bfr(g);
                }
            }
        }
    }
}

// grouped bf16-MFMA GEMM2; T3-minimum 2-phase (r8 structure).
__global__ __launch_bounds__(256) void k_mm2(
    const unsigned short* __restrict__ H, const unsigned short* __restrict__ W2b,
    const float* __restrict__ b2, const float* __restrict__ sb2,
    const int* __restrict__ t2e, const int* __restrict__ t2a,
    const int* __restrict__ offs, const int* __restrict__ total,
    const int* __restrict__ ltok, const float* __restrict__ lw,
    unsigned short* __restrict__ yslot, float* __restrict__ out)
{
    const int id = blockIdx.x;
    const int wg = (id & 7) * (NWG2 / 8) + (id >> 3);
    const int ns = wg / MAXT;
    const int tb = wg % MAXT;
    if (tb >= *total) return;
    const int e = t2e[tb];
    const int a0 = t2a[tb];
    const int acount = min(offs[e + 1] - a0, BM);
    const float* bb = (e < NE) ? (b2 + e * DD) : sb2;
    const int nb = ns * BN;

    __shared__ unsigned short As[2][BM * BK];
    __shared__ unsigned short Bs[2][BN * BK];
    __shared__ int rows[BM];
    __shared__ float wts[BM];
    const int tid = threadIdx.x;
    if (tid < BM) {
        rows[tid] = (tid < acount) ? ltok[a0 + tid] : -1;
        wts[tid]  = (tid < acount) ? lw[a0 + tid] : 0.f;
    }
    __syncthreads();

    const int wid = tid >> 6, lane = tid & 63;
    const int wr = wid >> 1, wc = wid & 1;
    const int l15 = lane & 15, l4 = lane >> 4;

    float bv[4];
    #pragma unroll
    for (int n = 0; n < 4; n++) bv[n] = bb[nb + wc * 64 + n * 16 + l15];

    f32x4 acc[4][4];
    #pragma unroll
    for (int m = 0; m < 4; m++)
        #pragma unroll
        for (int n = 0; n < 4; n++) acc[m][n] = (f32x4){0.f, 0.f, 0.f, 0.f};

    const unsigned short* aSrc[4];
    int Goff[4];
    #pragma unroll
    for (int c = 0; c < 4; c++) {
        int G = (wid * 4 + c) * 64 + lane;
        int row = G >> 3, j = G & 7;
        aSrc[c] = H + (size_t)(a0 + row) * HH + ((j ^ (row & 7)) << 3);  // contiguous rows
        Goff[c] = G * 8;
    }
    const unsigned short* wbase = W2b + ((size_t)e * KB2 * DD + nb) * 64;

    auto stage = [&](int buf, int kb) {
        #pragma unroll
        for (int c = 0; c < 4; c++)
            gl_lds16(aSrc[c] + kb * 64, &As[buf][Goff[c]]);
        const unsigned short* wb = wbase + (size_t)kb * (DD * 64);
        #pragma unroll
        for (int c = 0; c < 4; c++)
            gl_lds16(wb + Goff[c], &Bs[buf][Goff[c]]);
    };
    auto compute = [&](int buf) {
        #pragma unroll
        for (int kh = 0; kh < 2; kh++) {
            bf16x8 af[4], bf[4];
            #pragma unroll
            for (int f = 0; f < 4; f++) {
                int ar = wr * 64 + f * 16 + l15;
                int br = wc * 64 + f * 16 + l15;
                int pg = (kh << 2) + l4;
                af[f] = *(const bf16x8*)&As[buf][ar * 64 + ((pg ^ (ar & 7)) << 3)];
                bf[f] = *(const bf16x8*)&Bs[buf][br * 64 + ((pg ^ (br & 7)) << 3)];
            }
            #pragma unroll
            for (int m = 0; m < 4; m++)
                #pragma unroll
                for (int n = 0; n < 4; n++)
                    acc[m][n] = __builtin_amdgcn_mfma_f32_16x16x32_bf16(af[m], bf[n], acc[m][n], 0, 0, 0);
        }
    };

    stage(0, 0);
    WAIT_VM0();
    S_BARRIER();
    int cur = 0;
    #pragma unroll 1
    for (int kb = 0; kb < KB2; kb++) {
        if (kb + 1 < KB2) stage(cur ^ 1, kb + 1);
        __builtin_amdgcn_sched_barrier(0);
        compute(cur);
        if (kb + 1 < KB2) {
            WAIT_VM0();
            S_BARRIER();
            cur ^= 1;
        }
    }

    if (e == NE) {
        // shared expert: every token, weight 1 -> plain f32 stores (covers whole out body)
        #pragma unroll
        for (int m = 0; m < 4; m++) {
            int rbase = wr * 64 + m * 16 + l4 * 4;
            #pragma unroll
            for (int n = 0; n < 4; n++) {
                int col = nb + wc * 64 + n * 16 + l15;
                #pragma unroll
                for (int i = 0; i < 4; i++) {
                    int r = rbase + i;
                    out[(size_t)rows[r] * DD + col] = acc[m][n][i] + bv[n];
                }
            }
        }
    } else {
        // expert tile: weighted bf16 partial into its slot row (no races, no atomics)
        #pragma unroll
        for (int m = 0; m < 4; m++) {
            int rbase = wr * 64 + m * 16 + l4 * 4;
            #pragma unroll
            for (int n = 0; n < 4; n++) {
                int col = nb + wc * 64 + n * 16 + l15;
                #pragma unroll
                for (int i = 0; i < 4; i++) {
                    int r = rbase + i;
                    if (r < acount)
                        yslot[(size_t)(a0 + r) * DD + col] = bfr(wts[r] * (acc[m][n][i] + bv[n]));
                }
            }
        }
    }
}

// out[t,:] += sum_k yslot[sidx[t,k],:]
__global__ __launch_bounds__(256) void k_combine(
    const unsigned short* __restrict__ yslot, const int* __restrict__ sidx,
    float* __restrict__ out)
{
    const int t = blockIdx.x;
    const int s0 = sidx[t * 3 + 0], s1 = sidx[t * 3 + 1], s2 = sidx[t * 3 + 2];
    const int d = threadIdx.x * 4;
    float* o = out + (size_t)t * DD + d;
    float4 v = *(float4*)o;
    ushort4 a = *(const ushort4*)(yslot + (size_t)s0 * DD + d);
    ushort4 b = *(const ushort4*)(yslot + (size_t)s1 * DD + d);
    ushort4 c = *(const ushort4*)(yslot + (size_t)s2 * DD + d);
    v.x += b2f(a.x) + b2f(b.x) + b2f(c.x);
    v.y += b2f(a.y) + b2f(b.y) + b2f(c.y);
    v.z += b2f(a.z) + b2f(b.z) + b2f(c.z);
    v.w += b2f(a.w) + b2f(b.w) + b2f(c.w);
    *(float4*)o = v;
}

extern "C" void kernel_launch(void* const* d_in, const int* in_sizes, int n_in,
                              void* d_out, int out_size, void* d_ws, size_t ws_size,
                              hipStream_t stream)
{
    const float* x    = (const float*)d_in[0];
    const float* gW   = (const float*)d_in[1];
    const float* gb   = (const float*)d_in[2];
    const float* bias = (const float*)d_in[3];
    const float* W1   = (const float*)d_in[4];
    const float* b1   = (const float*)d_in[5];
    const float* W2   = (const float*)d_in[6];
    const float* b2   = (const float*)d_in[7];
    const float* sW1  = (const float*)d_in[8];
    const float* sb1  = (const float*)d_in[9];
    const float* sW2  = (const float*)d_in[10];
    const float* sb2  = (const float*)d_in[11];
    float* out = (float*)d_out;
    float* wsf = (float*)d_ws;
    int*   wsi = (int*)d_ws;

    int*   curs   = wsi + WS_CURS;
    int*   offs   = wsi + WS_OFFS;
    int*   total  = wsi + WS_TOTAL;
    int*   t2e    = wsi + WS_T2E;
    int*   t2a    = wsi + WS_T2A;
    int*   tokE   = wsi + WS_TOKE;
    float* tokW   = wsf + WS_TOKW;
    int*   ltok   = wsi + WS_LTOK;
    float* lwt    = wsf + WS_LW;
    float* Ppart  = wsf + WS_PPART;
    int*   Cpart  = wsi + WS_CPART;
    int*   sidx   = wsi + WS_SIDX;
    // counts/Psum: tuck into unused words right after curs (368..432)
    int*   counts = wsi + 432;
    float* Psum   = wsf + 464;
    unsigned short* xb  = (unsigned short*)((char*)d_ws + XB_OFF);
    unsigned short* Hb  = (unsigned short*)((char*)d_ws + H_OFF);
    unsigned short* W1b = (unsigned short*)((char*)d_ws + W1B_OFF);
    unsigned short* W2b = (unsigned short*)((char*)d_ws + W2B_OFF);
    unsigned short* yslot = W1b;   // reuse W1b region after k_mm1 is done

    k_gatecvt<<<CVT_TOT + GATE_BLKS, 256, 0, stream>>>(
        x, gW, gb, bias, W1, sW1, W2, sW2, tokE, tokW, Ppart, Cpart, xb, W1b, W2b);
    k_reduce<<<NE, 256, 0, stream>>>(Ppart, Cpart, counts, Psum);
    k_scan<<<1, 256, 0, stream>>>(counts, Psum, offs, total, t2e, t2a, curs,
                                  out + (size_t)TT * DD);
    k_scatter<<<TT / 256, 256, 0, stream>>>(tokE, tokW, offs, curs, ltok, lwt, sidx);
    k_mm1<<<NWG1, 256, 0, stream>>>(xb, W1b, b1, sb1, t2e, t2a, offs, total, ltok, Hb);
    k_mm2<<<NWG2, 256, 0, stream>>>(Hb, W2b, b2, sb2, t2e, t2a, offs, total, ltok, lwt,
                                    yslot, out);
    k_combine<<<TT, 256, 0, stream>>>(yslot, sidx, out);
}